// Round 14
// baseline (237.565 us; speedup 1.0000x reference)
//
#include <hip/hip_runtime.h>
#include <hip/hip_bf16.h>
#include <math.h>

#define NB 16
#define SS 64
#define HH 256
#define FAA 256

using short8 = __attribute__((ext_vector_type(8))) short;
using f32x4  = __attribute__((ext_vector_type(4))) float;

__device__ __forceinline__ unsigned int cvtpk(float a, float b) {
  unsigned int r;
  asm("v_cvt_pk_bf16_f32 %0, %1, %2" : "=v"(r) : "v"(a), "v"(b));  // RNE, a->lo b->hi
  return r;
}
// select a[q] without runtime vector indexing (dyn-indexed regs -> scratch)
__device__ __forceinline__ float sel4(const f32x4 a, int q) {
  const float s01 = (q & 1) ? a[1] : a[0];
  const float s23 = (q & 1) ? a[3] : a[2];
  return (q & 2) ? s23 : s01;
}

// ---------------------------------------------------------------------------
// Fused prolog, VECTORIZED: 8 elems/thread (2x float4 loads + 4x cvt_pk +
// one 16B store). Block map: [0,128) z1w | [128,192) wcat | [192,288) nmbf |
// [288,416) pm | [416,544) q | [544,800) fact_proj.
// wcat/nmbf K-PERMUTATION (storage (g*32+2l, g*32+2l+1) = actual cols
// (g*32+l, g*32+16+l)) vectorizes as two contiguous float4 gathers.
// gru_scan stores C in the same permuted order -> nm fusion invariant.
// ---------------------------------------------------------------------------
__global__ __launch_bounds__(256) void prolog_fused(
    const float* __restrict__ z1w, const float* __restrict__ Ur,
    const float* __restrict__ U, const float* __restrict__ nmw,
    const float* __restrict__ pm, const float* __restrict__ qs,
    unsigned short* __restrict__ z1wbf, unsigned short* __restrict__ wcatbf,
    unsigned short* __restrict__ nmbf, unsigned short* __restrict__ pmbf,
    unsigned short* __restrict__ qbf,
    const float* __restrict__ facts, const float* __restrict__ Wr,
    const float* __restrict__ Wrb, const float* __restrict__ Urb,
    const float* __restrict__ Ww, const float* __restrict__ Wb,
    float* __restrict__ FWr, float* __restrict__ FW) {
  __shared__ float fl[4][HH];
  const int bid = blockIdx.x, tid = threadIdx.x;

  auto cvt8 = [&](const float* src, unsigned short* dst, int base) {
    const float4 a = *(const float4*)(src + base);
    const float4 b = *(const float4*)(src + base + 4);
    uint4 o;
    o.x = cvtpk(a.x, a.y); o.y = cvtpk(a.z, a.w);
    o.z = cvtpk(b.x, b.y); o.w = cvtpk(b.z, b.w);
    *(uint4*)(dst + base) = o;  // base mult of 8 -> 16B aligned
  };
  // permuted pair-pack: storage u32 w holds (row[c0+w], row[c0+16+w])
  auto cvt8perm = [&](const float* row, unsigned short* dst, int sbase, int c0) {
    const float4 lo = *(const float4*)(row + c0);
    const float4 hi = *(const float4*)(row + c0 + 16);
    uint4 o;
    o.x = cvtpk(lo.x, hi.x); o.y = cvtpk(lo.y, hi.y);
    o.z = cvtpk(lo.z, hi.z); o.w = cvtpk(lo.w, hi.w);
    *(uint4*)(dst + sbase) = o;
  };

  if (bid < 128) {               // z1w: 262144 elems
    const int base = (bid * 256 + tid) * 8;
    cvt8(z1w, z1wbf, base);
    return;
  }
  if (bid < 192) {               // wcat: 131072 elems, K-permuted
    const int base = ((bid - 128) * 256 + tid) * 8;
    const int o = base >> 8, s0 = base & 255;
    const int gb = s0 & ~31, t0 = s0 & 31;          // t0 in {0,8,16,24}
    const float* row = (o < 256) ? (Ur + o * 256) : (U + (o - 256) * 256);
    cvt8perm(row, wcatbf, base, gb + (t0 >> 1));
    return;
  }
  if (bid < 288) {               // nmbf: 196608 elems, middle section permuted
    const int base = ((bid - 192) * 256 + tid) * 8;
    const int o = base / 768, k0 = base - o * 768;
    const float* row = nmw + o * 768;
    if (k0 >= 256 && k0 < 512) {
      const int s0 = k0 - 256, gb = s0 & ~31, t0 = s0 & 31;
      cvt8perm(row, nmbf, base, 256 + gb + (t0 >> 1));
    } else {
      cvt8(row, nmbf + o * 768, k0);
    }
    return;
  }
  if (bid < 416) {               // prevM: 262144 elems
    const int base = ((bid - 288) * 256 + tid) * 8;
    cvt8(pm, pmbf, base);
    return;
  }
  if (bid < 544) {               // questions: 262144 elems
    const int base = ((bid - 416) * 256 + tid) * 8;
    cvt8(qs, qbf, base);
    return;
  }
  // ---- fact_proj: FWr[b,h] = facts[b]·Wr[h]+Wr_b[h]+Ur_b[h]; FW = facts[b]·W[h]+W_b[h]
  const int b0 = (bid - 544) * 4;
#pragma unroll
  for (int r = 0; r < 4; ++r) fl[r][tid] = facts[(b0 + r) * HH + tid];
  __syncthreads();
  float ar[4] = {0.f, 0.f, 0.f, 0.f}, aw[4] = {0.f, 0.f, 0.f, 0.f};
  const float4* wr = (const float4*)(Wr + tid * HH);
  const float4* ww = (const float4*)(Ww + tid * HH);
#pragma unroll 4
  for (int d4 = 0; d4 < 64; ++d4) {
    float4 a = wr[d4], b = ww[d4];
#pragma unroll
    for (int r = 0; r < 4; ++r) {
      float4 f = *(const float4*)&fl[r][d4 * 4];  // LDS broadcast
      ar[r] += a.x * f.x + a.y * f.y + a.z * f.z + a.w * f.w;
      aw[r] += b.x * f.x + b.y * f.y + b.z * f.z + b.w * f.w;
    }
  }
  const float br = Wrb[tid] + Urb[tid], bw = Wb[tid];
#pragma unroll
  for (int r = 0; r < 4; ++r) {
    FWr[(b0 + r) * HH + tid] = ar[r] + br;
    FW[(b0 + r) * HH + tid] = aw[r] + bw;
  }
}

// ---------------------------------------------------------------------------
// Phase A: gate GEMM + FUSED masked softmax. Block = (n, 2 i's) = 128 rows,
// 256 cols, K=1024 as 32 chunks of 32 (c = hc*4+s; accumulation order
// bit-identical to prior rounds). PROVEN r12 version (switch-dispatch,
// rolled loop, counted-vmcnt triple-buffer) -- UNCHANGED.
// ---------------------------------------------------------------------------
__global__ __launch_bounds__(512, 4) void gate_gemm(
    const float* __restrict__ facts, const float* __restrict__ prevM,
    const float* __restrict__ questions, const unsigned short* __restrict__ z1wbf,
    const float* __restrict__ z1b, const float* __restrict__ z2w,
    const float* __restrict__ z2b, const int* __restrict__ doc_len,
    float* __restrict__ attn) {
  __shared__ unsigned short Ab[3][128 * 32];  // 8KB per buf
  __shared__ unsigned short Bb[3][256 * 32];  // 16KB per buf
  __shared__ float Gpart[128][4];

  const int bi = blockIdx.x;
  const int n = bi >> 5, i0 = (bi & 31) * 2;
  const int tid = threadIdx.x;
  const int w = tid >> 6, l = tid & 63;
  const int rg = w >> 2, cg = w & 3;        // rowgroup (2), colgroup (4)
  const int l15 = l & 15, q = l >> 4;
  const int t15 = tid & 15, jb = tid >> 4;  // builder mapping (jb 0..31)

  const float* fn = facts + n * SS * HH;
  const float* qn = questions + (n * SS + i0) * HH;
  const float* mn = prevM + (n * SS + i0) * HH;

  // stage B chunk c into Bb[buf]: wave w covers cols w*32..w*32+31; 2 loads/wave
  auto stageB = [&](int buf, int c) {
    const int kb = (c & 3) * 256 + (c >> 2) * 32;
    const int swz = ((l & 3) ^ ((l >> 2) & 3)) * 8;  // colg&3 == (l>>2)&3
#pragma unroll
    for (int j = 0; j < 2; ++j) {
      const int colg = w * 32 + j * 16 + (l >> 2);
      const unsigned short* src = z1wbf + colg * 1024 + kb + swz;
      __builtin_amdgcn_global_load_lds(src, Bb[buf] + (w * 32 + j * 16) * 32, 16, 0, 0);
    }
  };

  const int t15b = tid & 15;
  float2 Rf0, Rf1, Rq0, Rq1, Rm0, Rm1;  // current-hc operands (single set)

  // buildA with COMPILE-TIME s (instantiated 4x via uniform switch below)
  auto buildAs = [&](int buf, const int s) {
    unsigned int* dst = (unsigned int*)Ab[buf];
    const int dsw = t15b ^ ((jb & 3) << 2);  // swizzled 4B-slot (row&3 == jb&3)
    const float2 o0 = (s & 1) ? Rm0 : Rq0;   // folds: s literal
    const float2 o1 = (s & 1) ? Rm1 : Rq1;
#pragma unroll
    for (int pl = 0; pl < 2; ++pl) {
      const float fx = pl ? Rf1.x : Rf0.x;
      const float fy = pl ? Rf1.y : Rf0.y;
#pragma unroll
      for (int il = 0; il < 2; ++il) {
        const int row = il * 64 + pl * 32 + jb;
        const float ox = il ? o1.x : o0.x;
        const float oy = il ? o1.y : o0.y;
        float a, b;
        if (s < 2) { a = fx * ox;         b = fy * oy; }
        else       { a = fabsf(fx - ox);  b = fabsf(fy - oy); }
        dst[row * 16 + dsw] = cvtpk(a, b);
      }
    }
  };

  const f32x4 zero4 = {0.f, 0.f, 0.f, 0.f};
  f32x4 acc[4][4];
#pragma unroll
  for (int a = 0; a < 4; ++a)
#pragma unroll
    for (int b = 0; b < 4; ++b) acc[a][b] = zero4;

  auto mfmaStep = [&](int buf) {
    short8 Bfr[4];
#pragma unroll
    for (int nf = 0; nf < 4; ++nf) {
      const int col = cg * 64 + nf * 16 + l15;
      Bfr[nf] = *(const short8*)&Bb[buf][col * 32 + (q ^ (l15 & 3)) * 8];
    }
    __builtin_amdgcn_s_setprio(1);
#pragma unroll
    for (int mf = 0; mf < 4; ++mf) {
      const int row = rg * 64 + mf * 16 + l15;
      const short8 Afm = *(const short8*)&Ab[buf][row * 32 + (q ^ (l15 & 3)) * 8];
#pragma unroll
      for (int nf = 0; nf < 4; ++nf)
        acc[mf][nf] = __builtin_amdgcn_mfma_f32_16x16x32_bf16(Afm, Bfr[nf], acc[mf][nf], 0, 0, 0);
    }
    __builtin_amdgcn_s_setprio(0);
  };

  const int hh2 = t15 * 2;
  auto pf = [&](int hc) {
    const int h = hc * 32 + hh2;
    Rf0 = *(const float2*)(fn + jb * HH + h);
    Rf1 = *(const float2*)(fn + (jb + 32) * HH + h);
    Rq0 = *(const float2*)(qn + h);
    Rq1 = *(const float2*)(qn + HH + h);
    Rm0 = *(const float2*)(mn + h);
    Rm1 = *(const float2*)(mn + HH + h);
  };

  pf(0);
  stageB(0, 0);  // chunk 0 -> buf 0
  stageB(1, 1);  // chunk 1 -> buf 1
  buildAs(0, 0);
  // outstanding: pf(12) + chunk0(2) + chunk1(2); need pf+chunk0 landed -> vmcnt(2)
  asm volatile("s_waitcnt vmcnt(2) lgkmcnt(0)\n\ts_barrier" ::: "memory");

#pragma unroll 1
  for (int c = 0; c < 32; ++c) {  // ROLLED (pinned): r10 liveness, no spills
    const int s = c & 3, hc = c >> 2;
    const int cb = c % 3, nb2 = (c + 1) % 3, fb = (c + 2) % 3;

    // R dead at s==3 entry (last consumed by previous body's buildA);
    // pf latency hides under mfmaStep before buildA consumes R.
    if (s == 3 && hc < 7) pf(hc + 1);

    mfmaStep(cb);

    if (c + 2 < 32) stageB(fb, c + 2);         // youngest VMEM at barrier
    if (c + 1 < 32) {
      switch ((c + 1) & 3) {                   // wave-uniform SALU dispatch;
        case 0: buildAs(nb2, 0); break;        // each arm has LITERAL s ->
        case 1: buildAs(nb2, 1); break;        // selects/abs-branch fold
        case 2: buildAs(nb2, 2); break;
        case 3: buildAs(nb2, 3); break;
      }
    }

    // counted-vmcnt barrier: chunk c+1's 2 stage loads landed; chunk c+2's
    // stay in flight (pf loads drained by buildA's register dependency).
    if (c <= 29) {
      asm volatile("s_waitcnt vmcnt(2) lgkmcnt(0)\n\ts_barrier" ::: "memory");
    } else if (c == 30) {
      asm volatile("s_waitcnt vmcnt(0) lgkmcnt(0)\n\ts_barrier" ::: "memory");
    }
  }

  // epilogue: tanh, scale by z2_w, reduce over k
  float psum[4][4];
#pragma unroll
  for (int mf = 0; mf < 4; ++mf)
#pragma unroll
    for (int v = 0; v < 4; ++v) psum[mf][v] = 0.f;

#pragma unroll
  for (int nf = 0; nf < 4; ++nf) {
    const int k = cg * 64 + nf * 16 + l15;
    const float zb = z1b[k], zw = z2w[k];
#pragma unroll
    for (int mf = 0; mf < 4; ++mf)
#pragma unroll
      for (int v = 0; v < 4; ++v) {
        const float x = acc[mf][nf][v] + zb;
        const float e = __expf(2.f * x);
        const float t = 1.f - 2.f / (e + 1.f);  // tanh(x)
        psum[mf][v] += zw * t;
      }
  }
#pragma unroll
  for (int d = 1; d < 16; d <<= 1)
#pragma unroll
    for (int mf = 0; mf < 4; ++mf)
#pragma unroll
      for (int v = 0; v < 4; ++v) psum[mf][v] += __shfl_xor(psum[mf][v], d, 64);
  if (l15 == 0) {
#pragma unroll
    for (int mf = 0; mf < 4; ++mf)
#pragma unroll
      for (int v = 0; v < 4; ++v)
        Gpart[rg * 64 + mf * 16 + q * 4 + v][cg] = psum[mf][v];
  }
  __syncthreads();
  if (tid < 128) {  // waves 0,1 fully active: wave = row i, lane = j
    const float gg = Gpart[tid][0] + Gpart[tid][1] + Gpart[tid][2] + Gpart[tid][3] + z2b[0];
    const int i = i0 + (tid >> 6), j = tid & 63;
    const int dl = doc_len[n];
    const float x = (j < dl && gg != 0.0f) ? gg : -INFINITY;  // where(G*mask==0,-inf)
    float mx = x;
#pragma unroll
    for (int d = 1; d < 64; d <<= 1) mx = fmaxf(mx, __shfl_xor(mx, d, 64));
    const float e = (x == -INFINITY) ? 0.f : __expf(x - mx);
    float s = e;
#pragma unroll
    for (int d = 1; d < 64; d <<= 1) s += __shfl_xor(s, d, 64);
    attn[(n * SS + i) * SS + j] = e / s;
  }
}

// ---------------------------------------------------------------------------
// Phase C+D: GRU-style scan with FUSED next_mem tail. Block = (n, 4 rows),
// 256 blocks = all 256 CUs. Scan: proven r6 structure (rows dup'd 4x in M=16
// via broadcast A-read; lane (q,l15) updates row q; C stored K-PERMUTED in
// LDS, double-buffered, one barrier/step).
// FUSION: after t=63 the block's final C (rows i0..i0+3, K-permuted) sits in
// Cbf[0] -- exactly the layout nmbf's middle K-section expects. The block
// computes next_mem for its own 4 rows x 256 cols right here (384 MFMAs,
// ~1.5us tail): A from pmbf/qbf (global 16B/lane) + Cbf (LDS); B from nmbf.
// Deletes the next_mem kernel, its launch gap, and the cbf global round-trip.
// Per-column K accumulation is the serial 24-chain (pre-r12 proven order).
// ---------------------------------------------------------------------------
__global__ __launch_bounds__(512, 2) void gru_scan(
    const unsigned short* __restrict__ wcat, const float* __restrict__ FWr,
    const float* __restrict__ FW, const float* __restrict__ Ub,
    const float* __restrict__ attn,
    const unsigned short* __restrict__ pmbf, const unsigned short* __restrict__ qbf,
    const unsigned short* __restrict__ nmbf, const float* __restrict__ nmb,
    float* __restrict__ out) {
  __shared__ unsigned short Cbf[2][4 * 272];  // stride 272 sh (136 dw, 8 mod 32 -> 2-way)
  __shared__ float attn_sT[64 * 4];           // [t][row]

  const int bi = blockIdx.x, n = bi >> 4, i0 = (bi & 15) * 4;
  const int tid = threadIdx.x, w = tid >> 6, l = tid & 63;
  const int l15 = l & 15, q = l >> 4;
  const int h0 = w * 32 + l15;  // lane's actual h cols: h0 and h0+16

  // persistent B-fragments: f=0/1 -> Ur cols h0/h0+16 ; f=2/3 -> U cols (K perm'd)
  short8 Bf[8][4];
#pragma unroll
  for (int f = 0; f < 4; ++f) {
    const int wrow = ((f >> 1) ? 256 : 0) + w * 32 + (f & 1) * 16 + l15;
    const unsigned short* bb = wcat + wrow * 256 + q * 8;
#pragma unroll
    for (int kt = 0; kt < 8; ++kt)
      Bf[kt][f] = *(const short8*)(bb + kt * 32);
  }

  const float ub0 = Ub[h0], ub1 = Ub[h0 + 16];

  for (int e = tid; e < 64 * 4; e += 512)  // attn transposed: [t][row]
    attn_sT[e] = attn[(n * SS + i0 + (e & 3)) * SS + (e >> 2)];
  for (int e = tid; e < 544; e += 512)
    ((unsigned int*)Cbf[0])[e] = 0u;
  __syncthreads();

  const float* fwr_g = FWr + n * SS * HH;
  const float* fw_g  = FW + n * SS * HH;

  float cm0 = 0.f, cm1 = 0.f;  // fp32 master state: (row q, h0) and (row q, h0+16)
  float fr0 = fwr_g[h0], fr1 = fwr_g[h0 + 16];
  float fc0 = fw_g[h0],  fc1 = fw_g[h0 + 16];

  for (int t = 0; t < 64; ++t) {
    const int cur = t & 1;
    const unsigned short* Cr = Cbf[cur];
    unsigned int* Cw = (unsigned int*)Cbf[cur ^ 1];

    // A-fragments: row (l15&3) -> 4-way broadcast read
    short8 Af[8];
    const int arow = (l15 & 3) * 272;
#pragma unroll
    for (int kt = 0; kt < 8; ++kt)
      Af[kt] = *(const short8*)&Cr[arow + kt * 32 + q * 8];

    // prefetch next step's FWr/FW (consumed next iteration -> latency hidden)
    float nr0 = 0.f, nr1 = 0.f, nc0 = 0.f, nc1 = 0.f;
    if (t < 63) {
      nr0 = fwr_g[(t + 1) * HH + h0];
      nr1 = fwr_g[(t + 1) * HH + h0 + 16];
      nc0 = fw_g[(t + 1) * HH + h0];
      nc1 = fw_g[(t + 1) * HH + h0 + 16];
    }

    const f32x4 z4 = {0.f, 0.f, 0.f, 0.f};
    f32x4 a0 = z4, a1 = z4, a2 = z4, a3 = z4;
    __builtin_amdgcn_s_setprio(1);
#pragma unroll
    for (int kt = 0; kt < 8; ++kt) {
      a0 = __builtin_amdgcn_mfma_f32_16x16x32_bf16(Af[kt], Bf[kt][0], a0, 0, 0, 0);
      a2 = __builtin_amdgcn_mfma_f32_16x16x32_bf16(Af[kt], Bf[kt][2], a2, 0, 0, 0);
    }
#pragma unroll
    for (int kt = 0; kt < 8; ++kt) {
      a1 = __builtin_amdgcn_mfma_f32_16x16x32_bf16(Af[kt], Bf[kt][1], a1, 0, 0, 0);
      a3 = __builtin_amdgcn_mfma_f32_16x16x32_bf16(Af[kt], Bf[kt][3], a3, 0, 0, 0);
    }
    __builtin_amdgcn_s_setprio(0);

    const float g = attn_sT[t * 4 + q];  // 16-lane broadcast

    // cell 0 (needs a0,a2 only -> VALU overlaps a1/a3 MFMA pipe drain)
    const float yr0 = sel4(a0, q), yu0 = sel4(a2, q);
    const float r0 = 1.f / (1.f + __expf(-(fr0 + yr0)));
    const float x0 = fc0 + r0 * (yu0 + ub0);
    const float e0 = __expf(2.f * x0);
    const float h0t = 1.f - 2.f / (e0 + 1.f);
    cm0 += g * (h0t - cm0);

    // cell 1
    const float yr1 = sel4(a1, q), yu1 = sel4(a3, q);
    const float r1 = 1.f / (1.f + __expf(-(fr1 + yr1)));
    const float x1 = fc1 + r1 * (yu1 + ub1);
    const float e1 = __expf(2.f * x1);
    const float h1t = 1.f - 2.f / (e1 + 1.f);
    cm1 += g * (h1t - cm1);

    Cw[q * 136 + w * 16 + l15] = cvtpk(cm0, cm1);  // storage cols (2*l15, 2*l15+1)

    fr0 = nr0; fr1 = nr1; fc0 = nc0; fc1 = nc1;
    __syncthreads();  // single barrier: C writes complete before next Af reads
  }
  // final C (rows 0..3, K-permuted) is in Cbf[0]; loop-end barrier makes it
  // visible to all waves.

  // ---- FUSED next_mem: this block's 4 rows x 256 cols ----
  // Wave w covers cols w*32 + f*16 + l15 (f=0,1). A rows dup'd 4x (l15&3) ->
  // C/D slot m=q*4+v is actual row v; q-groups duplicate -> q==0 writes.
  {
    const int ar4 = (n * SS + i0 + (l15 & 3)) * HH + q * 8;
    const unsigned short* pmA = pmbf + ar4;
    const unsigned short* qA  = qbf + ar4;
    const int carow = (l15 & 3) * 272 + q * 8;
    const f32x4 z4 = {0.f, 0.f, 0.f, 0.f};
    f32x4 nacc[2];
#pragma unroll
    for (int f = 0; f < 2; ++f) {
      const unsigned short* nb = nmbf + (w * 32 + f * 16 + l15) * 768 + q * 8;
      f32x4 a = z4;
#pragma unroll
      for (int kt = 0; kt < 8; ++kt) {  // K section 0: prevM
        const short8 Afm = *(const short8*)(pmA + kt * 32);
        const short8 Bfm = *(const short8*)(nb + kt * 32);
        a = __builtin_amdgcn_mfma_f32_16x16x32_bf16(Afm, Bfm, a, 0, 0, 0);
      }
#pragma unroll
      for (int kt = 0; kt < 8; ++kt) {  // K section 1: C (LDS, K-permuted)
        const short8 Afm = *(const short8*)&Cbf[0][carow + kt * 32];
        const short8 Bfm = *(const short8*)(nb + 256 + kt * 32);
        a = __builtin_amdgcn_mfma_f32_16x16x32_bf16(Afm, Bfm, a, 0, 0, 0);
      }
#pragma unroll
      for (int kt = 0; kt < 8; ++kt) {  // K section 2: questions
        const short8 Afm = *(const short8*)(qA + kt * 32);
        const short8 Bfm = *(const short8*)(nb + 512 + kt * 32);
        a = __builtin_amdgcn_mfma_f32_16x16x32_bf16(Afm, Bfm, a, 0, 0, 0);
      }
      nacc[f] = a;
    }
    if (q == 0) {
#pragma unroll
      for (int f = 0; f < 2; ++f) {
        const int col = w * 32 + f * 16 + l15;
        const float bv = nmb[col];
        const f32x4 a = f ? nacc[1] : nacc[0];
#pragma unroll
        for (int v = 0; v < 4; ++v)
          out[(n * SS + i0 + v) * HH + col] = fmaxf(a[v] + bv, 0.f);
      }
    }
  }
}

// ---------------------------------------------------------------------------
extern "C" void kernel_launch(void* const* d_in, const int* in_sizes, int n_in,
                              void* d_out, int out_size, void* d_ws, size_t ws_size,
                              hipStream_t stream) {
  const float* facts     = (const float*)d_in[0];
  const float* prevM     = (const float*)d_in[1];
  const float* questions = (const float*)d_in[2];
  const int*   doc_len   = (const int*)d_in[3];
  const float* z1w = (const float*)d_in[4];
  const float* z1b = (const float*)d_in[5];
  const float* z2w = (const float*)d_in[6];
  const float* z2b = (const float*)d_in[7];
  const float* Wrw = (const float*)d_in[8];
  const float* Wrb = (const float*)d_in[9];
  const float* Urw = (const float*)d_in[10];
  const float* Urb = (const float*)d_in[11];
  const float* Ww  = (const float*)d_in[12];
  const float* Wb  = (const float*)d_in[13];
  const float* Uw  = (const float*)d_in[14];
  const float* Ub  = (const float*)d_in[15];
  const float* nmw = (const float*)d_in[16];
  const float* nmb = (const float*)d_in[17];

  char* ws = (char*)d_ws;
  unsigned short* z1wbf  = (unsigned short*)(ws + 0);        // 512 KB
  unsigned short* wcatbf = (unsigned short*)(ws + 524288);   // 256 KB
  unsigned short* nmbf   = (unsigned short*)(ws + 786432);   // 384 KB
  unsigned short* pmbf   = (unsigned short*)(ws + 1179648);  // 512 KB
  unsigned short* qbf    = (unsigned short*)(ws + 1703936);  // 512 KB
  float* FWr = (float*)(ws + 2490368);                       // 1 MB
  float* FW  = (float*)(ws + 3538944);                       // 1 MB

  float* out  = (float*)d_out;
  float* attn = out + NB * SS * HH;  // second output region

  prolog_fused<<<800, 256, 0, stream>>>(z1w, Urw, Uw, nmw, prevM, questions,
                                        z1wbf, wcatbf, nmbf, pmbf, qbf,
                                        facts, Wrw, Wrb, Urb, Ww, Wb, FWr, FW);
  gate_gemm<<<512, 512, 0, stream>>>(facts, prevM, questions, z1wbf, z1b, z2w, z2b,
                                     doc_len, attn);
  gru_scan<<<256, 512, 0, stream>>>(wcatbf, FWr, FW, Ub, attn,
                                    pmbf, qbf, nmbf, nmb, out);
}

// Round 15
// 227.482 us; speedup vs baseline: 1.0443x; 1.0443x over previous
//
#include <hip/hip_runtime.h>
#include <hip/hip_bf16.h>
#include <math.h>

#define NB 16
#define SS 64
#define HH 256
#define FAA 256

using short8 = __attribute__((ext_vector_type(8))) short;
using f32x4  = __attribute__((ext_vector_type(4))) float;

__device__ __forceinline__ unsigned int cvtpk(float a, float b) {
  unsigned int r;
  asm("v_cvt_pk_bf16_f32 %0, %1, %2" : "=v"(r) : "v"(a), "v"(b));  // RNE, a->lo b->hi
  return r;
}
// select a[q] without runtime vector indexing (dyn-indexed regs -> scratch)
__device__ __forceinline__ float sel4(const f32x4 a, int q) {
  const float s01 = (q & 1) ? a[1] : a[0];
  const float s23 = (q & 1) ? a[3] : a[2];
  return (q & 2) ? s23 : s01;
}

// ---------------------------------------------------------------------------
// Fused prolog, VECTORIZED: 8 elems/thread (2x float4 loads + 4x cvt_pk +
// one 16B store). Block map: [0,128) z1w | [128,192) wcat | [192,288) nmbf |
// [288,416) pm | [416,544) q | [544,800) fact_proj.
// wcat/nmbf K-PERMUTATION (storage (g*32+2l, g*32+2l+1) = actual cols
// (g*32+l, g*32+16+l)) vectorizes as two contiguous float4 gathers.
// gru_scan stores C in the same permuted order -> phase D invariant.
// ---------------------------------------------------------------------------
__global__ __launch_bounds__(256) void prolog_fused(
    const float* __restrict__ z1w, const float* __restrict__ Ur,
    const float* __restrict__ U, const float* __restrict__ nmw,
    const float* __restrict__ pm, const float* __restrict__ qs,
    unsigned short* __restrict__ z1wbf, unsigned short* __restrict__ wcatbf,
    unsigned short* __restrict__ nmbf, unsigned short* __restrict__ pmbf,
    unsigned short* __restrict__ qbf,
    const float* __restrict__ facts, const float* __restrict__ Wr,
    const float* __restrict__ Wrb, const float* __restrict__ Urb,
    const float* __restrict__ Ww, const float* __restrict__ Wb,
    float* __restrict__ FWr, float* __restrict__ FW) {
  __shared__ float fl[4][HH];
  const int bid = blockIdx.x, tid = threadIdx.x;

  auto cvt8 = [&](const float* src, unsigned short* dst, int base) {
    const float4 a = *(const float4*)(src + base);
    const float4 b = *(const float4*)(src + base + 4);
    uint4 o;
    o.x = cvtpk(a.x, a.y); o.y = cvtpk(a.z, a.w);
    o.z = cvtpk(b.x, b.y); o.w = cvtpk(b.z, b.w);
    *(uint4*)(dst + base) = o;  // base mult of 8 -> 16B aligned
  };
  // permuted pair-pack: storage u32 w holds (row[c0+w], row[c0+16+w])
  auto cvt8perm = [&](const float* row, unsigned short* dst, int sbase, int c0) {
    const float4 lo = *(const float4*)(row + c0);
    const float4 hi = *(const float4*)(row + c0 + 16);
    uint4 o;
    o.x = cvtpk(lo.x, hi.x); o.y = cvtpk(lo.y, hi.y);
    o.z = cvtpk(lo.z, hi.z); o.w = cvtpk(lo.w, hi.w);
    *(uint4*)(dst + sbase) = o;
  };

  if (bid < 128) {               // z1w: 262144 elems
    const int base = (bid * 256 + tid) * 8;
    cvt8(z1w, z1wbf, base);
    return;
  }
  if (bid < 192) {               // wcat: 131072 elems, K-permuted
    const int base = ((bid - 128) * 256 + tid) * 8;
    const int o = base >> 8, s0 = base & 255;
    const int gb = s0 & ~31, t0 = s0 & 31;          // t0 in {0,8,16,24}
    const float* row = (o < 256) ? (Ur + o * 256) : (U + (o - 256) * 256);
    cvt8perm(row, wcatbf, base, gb + (t0 >> 1));
    return;
  }
  if (bid < 288) {               // nmbf: 196608 elems, middle section permuted
    const int base = ((bid - 192) * 256 + tid) * 8;
    const int o = base / 768, k0 = base - o * 768;
    const float* row = nmw + o * 768;
    if (k0 >= 256 && k0 < 512) {
      const int s0 = k0 - 256, gb = s0 & ~31, t0 = s0 & 31;
      cvt8perm(row, nmbf, base, 256 + gb + (t0 >> 1));
    } else {
      cvt8(row, nmbf + o * 768, k0);
    }
    return;
  }
  if (bid < 416) {               // prevM: 262144 elems
    const int base = ((bid - 288) * 256 + tid) * 8;
    cvt8(pm, pmbf, base);
    return;
  }
  if (bid < 544) {               // questions: 262144 elems
    const int base = ((bid - 416) * 256 + tid) * 8;
    cvt8(qs, qbf, base);
    return;
  }
  // ---- fact_proj: FWr[b,h] = facts[b]·Wr[h]+Wr_b[h]+Ur_b[h]; FW = facts[b]·W[h]+W_b[h]
  const int b0 = (bid - 544) * 4;
#pragma unroll
  for (int r = 0; r < 4; ++r) fl[r][tid] = facts[(b0 + r) * HH + tid];
  __syncthreads();
  float ar[4] = {0.f, 0.f, 0.f, 0.f}, aw[4] = {0.f, 0.f, 0.f, 0.f};
  const float4* wr = (const float4*)(Wr + tid * HH);
  const float4* ww = (const float4*)(Ww + tid * HH);
#pragma unroll 4
  for (int d4 = 0; d4 < 64; ++d4) {
    float4 a = wr[d4], b = ww[d4];
#pragma unroll
    for (int r = 0; r < 4; ++r) {
      float4 f = *(const float4*)&fl[r][d4 * 4];  // LDS broadcast
      ar[r] += a.x * f.x + a.y * f.y + a.z * f.z + a.w * f.w;
      aw[r] += b.x * f.x + b.y * f.y + b.z * f.z + b.w * f.w;
    }
  }
  const float br = Wrb[tid] + Urb[tid], bw = Wb[tid];
#pragma unroll
  for (int r = 0; r < 4; ++r) {
    FWr[(b0 + r) * HH + tid] = ar[r] + br;
    FW[(b0 + r) * HH + tid] = aw[r] + bw;
  }
}

// ---------------------------------------------------------------------------
// Phase A: gate GEMM + FUSED masked softmax. Block = (n, 2 i's) = 128 rows,
// 256 cols, K=1024 as 32 chunks of 32 (c = hc*4+s; accumulation order
// bit-identical to prior rounds). PROVEN r12 version (switch-dispatch,
// rolled loop, counted-vmcnt triple-buffer) -- UNCHANGED.
// ---------------------------------------------------------------------------
__global__ __launch_bounds__(512, 4) void gate_gemm(
    const float* __restrict__ facts, const float* __restrict__ prevM,
    const float* __restrict__ questions, const unsigned short* __restrict__ z1wbf,
    const float* __restrict__ z1b, const float* __restrict__ z2w,
    const float* __restrict__ z2b, const int* __restrict__ doc_len,
    float* __restrict__ attn) {
  __shared__ unsigned short Ab[3][128 * 32];  // 8KB per buf
  __shared__ unsigned short Bb[3][256 * 32];  // 16KB per buf
  __shared__ float Gpart[128][4];

  const int bi = blockIdx.x;
  const int n = bi >> 5, i0 = (bi & 31) * 2;
  const int tid = threadIdx.x;
  const int w = tid >> 6, l = tid & 63;
  const int rg = w >> 2, cg = w & 3;        // rowgroup (2), colgroup (4)
  const int l15 = l & 15, q = l >> 4;
  const int t15 = tid & 15, jb = tid >> 4;  // builder mapping (jb 0..31)

  const float* fn = facts + n * SS * HH;
  const float* qn = questions + (n * SS + i0) * HH;
  const float* mn = prevM + (n * SS + i0) * HH;

  // stage B chunk c into Bb[buf]: wave w covers cols w*32..w*32+31; 2 loads/wave
  auto stageB = [&](int buf, int c) {
    const int kb = (c & 3) * 256 + (c >> 2) * 32;
    const int swz = ((l & 3) ^ ((l >> 2) & 3)) * 8;  // colg&3 == (l>>2)&3
#pragma unroll
    for (int j = 0; j < 2; ++j) {
      const int colg = w * 32 + j * 16 + (l >> 2);
      const unsigned short* src = z1wbf + colg * 1024 + kb + swz;
      __builtin_amdgcn_global_load_lds(src, Bb[buf] + (w * 32 + j * 16) * 32, 16, 0, 0);
    }
  };

  const int t15b = tid & 15;
  float2 Rf0, Rf1, Rq0, Rq1, Rm0, Rm1;  // current-hc operands (single set)

  // buildA with COMPILE-TIME s (instantiated 4x via uniform switch below)
  auto buildAs = [&](int buf, const int s) {
    unsigned int* dst = (unsigned int*)Ab[buf];
    const int dsw = t15b ^ ((jb & 3) << 2);  // swizzled 4B-slot (row&3 == jb&3)
    const float2 o0 = (s & 1) ? Rm0 : Rq0;   // folds: s literal
    const float2 o1 = (s & 1) ? Rm1 : Rq1;
#pragma unroll
    for (int pl = 0; pl < 2; ++pl) {
      const float fx = pl ? Rf1.x : Rf0.x;
      const float fy = pl ? Rf1.y : Rf0.y;
#pragma unroll
      for (int il = 0; il < 2; ++il) {
        const int row = il * 64 + pl * 32 + jb;
        const float ox = il ? o1.x : o0.x;
        const float oy = il ? o1.y : o0.y;
        float a, b;
        if (s < 2) { a = fx * ox;         b = fy * oy; }
        else       { a = fabsf(fx - ox);  b = fabsf(fy - oy); }
        dst[row * 16 + dsw] = cvtpk(a, b);
      }
    }
  };

  const f32x4 zero4 = {0.f, 0.f, 0.f, 0.f};
  f32x4 acc[4][4];
#pragma unroll
  for (int a = 0; a < 4; ++a)
#pragma unroll
    for (int b = 0; b < 4; ++b) acc[a][b] = zero4;

  auto mfmaStep = [&](int buf) {
    short8 Bfr[4];
#pragma unroll
    for (int nf = 0; nf < 4; ++nf) {
      const int col = cg * 64 + nf * 16 + l15;
      Bfr[nf] = *(const short8*)&Bb[buf][col * 32 + (q ^ (l15 & 3)) * 8];
    }
    __builtin_amdgcn_s_setprio(1);
#pragma unroll
    for (int mf = 0; mf < 4; ++mf) {
      const int row = rg * 64 + mf * 16 + l15;
      const short8 Afm = *(const short8*)&Ab[buf][row * 32 + (q ^ (l15 & 3)) * 8];
#pragma unroll
      for (int nf = 0; nf < 4; ++nf)
        acc[mf][nf] = __builtin_amdgcn_mfma_f32_16x16x32_bf16(Afm, Bfr[nf], acc[mf][nf], 0, 0, 0);
    }
    __builtin_amdgcn_s_setprio(0);
  };

  const int hh2 = t15 * 2;
  auto pf = [&](int hc) {
    const int h = hc * 32 + hh2;
    Rf0 = *(const float2*)(fn + jb * HH + h);
    Rf1 = *(const float2*)(fn + (jb + 32) * HH + h);
    Rq0 = *(const float2*)(qn + h);
    Rq1 = *(const float2*)(qn + HH + h);
    Rm0 = *(const float2*)(mn + h);
    Rm1 = *(const float2*)(mn + HH + h);
  };

  pf(0);
  stageB(0, 0);  // chunk 0 -> buf 0
  stageB(1, 1);  // chunk 1 -> buf 1
  buildAs(0, 0);
  // outstanding: pf(12) + chunk0(2) + chunk1(2); need pf+chunk0 landed -> vmcnt(2)
  asm volatile("s_waitcnt vmcnt(2) lgkmcnt(0)\n\ts_barrier" ::: "memory");

#pragma unroll 1
  for (int c = 0; c < 32; ++c) {  // ROLLED (pinned): r10 liveness, no spills
    const int s = c & 3, hc = c >> 2;
    const int cb = c % 3, nb2 = (c + 1) % 3, fb = (c + 2) % 3;

    // R dead at s==3 entry (last consumed by previous body's buildA);
    // pf latency hides under mfmaStep before buildA consumes R.
    if (s == 3 && hc < 7) pf(hc + 1);

    mfmaStep(cb);

    if (c + 2 < 32) stageB(fb, c + 2);         // youngest VMEM at barrier
    if (c + 1 < 32) {
      switch ((c + 1) & 3) {                   // wave-uniform SALU dispatch;
        case 0: buildAs(nb2, 0); break;        // each arm has LITERAL s ->
        case 1: buildAs(nb2, 1); break;        // selects/abs-branch fold
        case 2: buildAs(nb2, 2); break;
        case 3: buildAs(nb2, 3); break;
      }
    }

    // counted-vmcnt barrier: chunk c+1's 2 stage loads landed; chunk c+2's
    // stay in flight (pf loads drained by buildA's register dependency).
    if (c <= 29) {
      asm volatile("s_waitcnt vmcnt(2) lgkmcnt(0)\n\ts_barrier" ::: "memory");
    } else if (c == 30) {
      asm volatile("s_waitcnt vmcnt(0) lgkmcnt(0)\n\ts_barrier" ::: "memory");
    }
  }

  // epilogue: tanh, scale by z2_w, reduce over k
  float psum[4][4];
#pragma unroll
  for (int mf = 0; mf < 4; ++mf)
#pragma unroll
    for (int v = 0; v < 4; ++v) psum[mf][v] = 0.f;

#pragma unroll
  for (int nf = 0; nf < 4; ++nf) {
    const int k = cg * 64 + nf * 16 + l15;
    const float zb = z1b[k], zw = z2w[k];
#pragma unroll
    for (int mf = 0; mf < 4; ++mf)
#pragma unroll
      for (int v = 0; v < 4; ++v) {
        const float x = acc[mf][nf][v] + zb;
        const float e = __expf(2.f * x);
        const float t = 1.f - 2.f / (e + 1.f);  // tanh(x)
        psum[mf][v] += zw * t;
      }
  }
#pragma unroll
  for (int d = 1; d < 16; d <<= 1)
#pragma unroll
    for (int mf = 0; mf < 4; ++mf)
#pragma unroll
      for (int v = 0; v < 4; ++v) psum[mf][v] += __shfl_xor(psum[mf][v], d, 64);
  if (l15 == 0) {
#pragma unroll
    for (int mf = 0; mf < 4; ++mf)
#pragma unroll
      for (int v = 0; v < 4; ++v)
        Gpart[rg * 64 + mf * 16 + q * 4 + v][cg] = psum[mf][v];
  }
  __syncthreads();
  if (tid < 128) {  // waves 0,1 fully active: wave = row i, lane = j
    const float gg = Gpart[tid][0] + Gpart[tid][1] + Gpart[tid][2] + Gpart[tid][3] + z2b[0];
    const int i = i0 + (tid >> 6), j = tid & 63;
    const int dl = doc_len[n];
    const float x = (j < dl && gg != 0.0f) ? gg : -INFINITY;  // where(G*mask==0,-inf)
    float mx = x;
#pragma unroll
    for (int d = 1; d < 64; d <<= 1) mx = fmaxf(mx, __shfl_xor(mx, d, 64));
    const float e = (x == -INFINITY) ? 0.f : __expf(x - mx);
    float s = e;
#pragma unroll
    for (int d = 1; d < 64; d <<= 1) s += __shfl_xor(s, d, 64);
    attn[(n * SS + i) * SS + l] = e / s;
  }
}

// ---------------------------------------------------------------------------
// Phase C: GRU-style scan, single 64-step kernel (proven r6 version, ~74us,
// near its structural floor: per-CU per-step MFMA quantum is invariant under
// all re-partitions analyzed; r14's nm-fusion tail cost +12us and was
// reverted). Block = (n, 4 rows), 256 blocks = all 256 CUs.
// Rows dup'd 4x in M=16 (broadcast A-read); lane (q,l15) updates row q only.
// C stored K-PERMUTED. UNCHANGED from r13.
// ---------------------------------------------------------------------------
__global__ __launch_bounds__(512, 2) void gru_scan(
    const unsigned short* __restrict__ wcat, const float* __restrict__ FWr,
    const float* __restrict__ FW, const float* __restrict__ Ub,
    const float* __restrict__ attn, unsigned short* __restrict__ Cout) {
  __shared__ unsigned short Cbf[2][4 * 272];  // stride 272 sh (136 dw, 8 mod 32 -> 2-way)
  __shared__ float attn_sT[64 * 4];           // [t][row]

  const int bi = blockIdx.x, n = bi >> 4, i0 = (bi & 15) * 4;
  const int tid = threadIdx.x, w = tid >> 6, l = tid & 63;
  const int l15 = l & 15, q = l >> 4;
  const int h0 = w * 32 + l15;  // lane's actual h cols: h0 and h0+16

  // persistent B-fragments: f=0/1 -> Ur cols h0/h0+16 ; f=2/3 -> U cols (K perm'd)
  short8 Bf[8][4];
#pragma unroll
  for (int f = 0; f < 4; ++f) {
    const int wrow = ((f >> 1) ? 256 : 0) + w * 32 + (f & 1) * 16 + l15;
    const unsigned short* bb = wcat + wrow * 256 + q * 8;
#pragma unroll
    for (int kt = 0; kt < 8; ++kt)
      Bf[kt][f] = *(const short8*)(bb + kt * 32);
  }

  const float ub0 = Ub[h0], ub1 = Ub[h0 + 16];

  for (int e = tid; e < 64 * 4; e += 512)  // attn transposed: [t][row]
    attn_sT[e] = attn[(n * SS + i0 + (e & 3)) * SS + (e >> 2)];
  for (int e = tid; e < 544; e += 512)
    ((unsigned int*)Cbf[0])[e] = 0u;
  __syncthreads();

  const float* fwr_g = FWr + n * SS * HH;
  const float* fw_g  = FW + n * SS * HH;

  float cm0 = 0.f, cm1 = 0.f;  // fp32 master state: (row q, h0) and (row q, h0+16)
  float fr0 = fwr_g[h0], fr1 = fwr_g[h0 + 16];
  float fc0 = fw_g[h0],  fc1 = fw_g[h0 + 16];

  for (int t = 0; t < 64; ++t) {
    const int cur = t & 1;
    const unsigned short* Cr = Cbf[cur];
    unsigned int* Cw = (unsigned int*)Cbf[cur ^ 1];

    // A-fragments: row (l15&3) -> 4-way broadcast read
    short8 Af[8];
    const int arow = (l15 & 3) * 272;
#pragma unroll
    for (int kt = 0; kt < 8; ++kt)
      Af[kt] = *(const short8*)&Cr[arow + kt * 32 + q * 8];

    // prefetch next step's FWr/FW (consumed next iteration -> latency hidden)
    float nr0 = 0.f, nr1 = 0.f, nc0 = 0.f, nc1 = 0.f;
    if (t < 63) {
      nr0 = fwr_g[(t + 1) * HH + h0];
      nr1 = fwr_g[(t + 1) * HH + h0 + 16];
      nc0 = fw_g[(t + 1) * HH + h0];
      nc1 = fw_g[(t + 1) * HH + h0 + 16];
    }

    const f32x4 z4 = {0.f, 0.f, 0.f, 0.f};
    f32x4 a0 = z4, a1 = z4, a2 = z4, a3 = z4;
    __builtin_amdgcn_s_setprio(1);
#pragma unroll
    for (int kt = 0; kt < 8; ++kt) {
      a0 = __builtin_amdgcn_mfma_f32_16x16x32_bf16(Af[kt], Bf[kt][0], a0, 0, 0, 0);
      a2 = __builtin_amdgcn_mfma_f32_16x16x32_bf16(Af[kt], Bf[kt][2], a2, 0, 0, 0);
    }
#pragma unroll
    for (int kt = 0; kt < 8; ++kt) {
      a1 = __builtin_amdgcn_mfma_f32_16x16x32_bf16(Af[kt], Bf[kt][1], a1, 0, 0, 0);
      a3 = __builtin_amdgcn_mfma_f32_16x16x32_bf16(Af[kt], Bf[kt][3], a3, 0, 0, 0);
    }
    __builtin_amdgcn_s_setprio(0);

    const float g = attn_sT[t * 4 + q];  // 16-lane broadcast

    // cell 0 (needs a0,a2 only -> VALU overlaps a1/a3 MFMA pipe drain)
    const float yr0 = sel4(a0, q), yu0 = sel4(a2, q);
    const float r0 = 1.f / (1.f + __expf(-(fr0 + yr0)));
    const float x0 = fc0 + r0 * (yu0 + ub0);
    const float e0 = __expf(2.f * x0);
    const float h0t = 1.f - 2.f / (e0 + 1.f);
    cm0 += g * (h0t - cm0);

    // cell 1
    const float yr1 = sel4(a1, q), yu1 = sel4(a3, q);
    const float r1 = 1.f / (1.f + __expf(-(fr1 + yr1)));
    const float x1 = fc1 + r1 * (yu1 + ub1);
    const float e1 = __expf(2.f * x1);
    const float h1t = 1.f - 2.f / (e1 + 1.f);
    cm1 += g * (h1t - cm1);

    Cw[q * 136 + w * 16 + l15] = cvtpk(cm0, cm1);  // storage cols (2*l15, 2*l15+1)

    fr0 = nr0; fr1 = nr1; fc0 = nc0; fc1 = nc1;
    __syncthreads();  // single barrier: C writes complete before next Af reads
  }

  // final state in Cbf[0] (t=63 wrote buf 0); 4 rows x 128 dwords
  {
    const int row = tid >> 7, wo = tid & 127;
    ((unsigned int*)Cout)[(n * SS + i0 + row) * 128 + wo] =
        *(const unsigned int*)&Cbf[0][row * 272 + wo * 2];
  }
}

// ---------------------------------------------------------------------------
// Phase D: next_mem = relu([prevM | C | questions] @ nm_w^T + nm_b)
// r12 proven version: tile 32 rows x 16 cols -> 512 blocks = 2 blocks/CU,
// 4 waves (rh = w&1 row half, kh = w>>1 K half), 12-kt chains, 2KB LDS
// partial-combine. UNCHANGED from r13.
// ---------------------------------------------------------------------------
__global__ __launch_bounds__(256) void next_mem_gemm(
    const unsigned short* __restrict__ pmbf, const unsigned short* __restrict__ cbf,
    const unsigned short* __restrict__ qbf, const unsigned short* __restrict__ nmbf,
    const float* __restrict__ nmb, float* __restrict__ out) {
  __shared__ float part[2][64][4];  // kh=1 partials: [rh][lane][v]
  const int bi = blockIdx.x;
  const int rb = bi >> 4, cb = bi & 15;
  const int r0 = rb * 32, c0 = cb * 16;
  const int tid = threadIdx.x, w = tid >> 6, l = tid & 63;
  const int rh = w & 1, kh = w >> 1;
  const int l15 = l & 15, q = l >> 4;

  const int arow = (r0 + rh * 16 + l15) * HH + q * 8;  // A: per-lane row, 16B slice
  const unsigned short* nb = nmbf + (c0 + l15) * 768 + q * 8;

  f32x4 acc = {0.f, 0.f, 0.f, 0.f};
#pragma unroll
  for (int j = 0; j < 12; ++j) {
    const int kt = kh * 12 + j;                 // wave-uniform
    const unsigned short* asrc = (kt < 8) ? pmbf : ((kt < 16) ? cbf : qbf);
    const short8 Af = *(const short8*)(asrc + arow + (kt & 7) * 32);
    const short8 Bf = *(const short8*)(nb + kt * 32);
    acc = __builtin_amdgcn_mfma_f32_16x16x32_bf16(Af, Bf, acc, 0, 0, 0);
  }

  if (kh == 1) {
#pragma unroll
    for (int v = 0; v < 4; ++v) part[rh][l][v] = acc[v];
  }
  __syncthreads();
  if (kh == 0) {
    const int col = c0 + l15;
    const float bv = nmb[col];
#pragma unroll
    for (int v = 0; v < 4; ++v) {
      const float s = acc[v] + part[rh][l][v];
      out[(r0 + rh * 16 + q * 4 + v) * HH + col] = fmaxf(s + bv, 0.f);
    }
  }
}

// ---------------------------------------------------------------------------
extern "C" void kernel_launch(void* const* d_in, const int* in_sizes, int n_in,
                              void* d_out, int out_size, void* d_ws, size_t ws_size,
                              hipStream_t stream) {
  const float* facts     = (const float*)d_in[0];
  const float* prevM     = (const float*)d_in[1];
  const float* questions = (const float*)d_in[2];
  const int*   doc_len   = (const int*)d_in[3];
  const float* z1w = (const float*)d_in[4];
  const float* z1b = (const float*)d_in[5];
  const float* z2w = (const float*)d_in[6];
  const float* z2b = (const float*)d_in[7];
  const float* Wrw = (const float*)d_in[8];
  const float* Wrb = (const float*)d_in[9];
  const float* Urw = (const float*)d_in[10];
  const float* Urb = (const float*)d_in[11];
  const float* Ww  = (const float*)d_in[12];
  const float* Wb  = (const float*)d_in[13];
  const float* Uw  = (const float*)d_in[14];
  const float* Ub  = (const float*)d_in[15];
  const float* nmw = (const float*)d_in[16];
  const float* nmb = (const float*)d_in[17];

  char* ws = (char*)d_ws;
  unsigned short* z1wbf  = (unsigned short*)(ws + 0);        // 512 KB
  unsigned short* wcatbf = (unsigned short*)(ws + 524288);   // 256 KB
  unsigned short* nmbf   = (unsigned short*)(ws + 786432);   // 384 KB
  unsigned short* pmbf   = (unsigned short*)(ws + 1179648);  // 512 KB
  unsigned short* qbf    = (unsigned short*)(ws + 1703936);  // 512 KB
  float* FWr = (float*)(ws + 2490368);                       // 1 MB
  float* FW  = (float*)(ws + 3538944);                       // 1 MB
  unsigned short* cbf = (unsigned short*)(ws + 4587520);     // 512 KB  (total ~4.9 MB)

  float* out  = (float*)d_out;
  float* attn = out + NB * SS * HH;  // second output region

  prolog_fused<<<800, 256, 0, stream>>>(z1w, Urw, Uw, nmw, prevM, questions,
                                        z1wbf, wcatbf, nmbf, pmbf, qbf,
                                        facts, Wrw, Wrb, Urb, Ww, Wb, FWr, FW);
  gate_gemm<<<512, 512, 0, stream>>>(facts, prevM, questions, z1wbf, z1b, z2w, z2b,
                                     doc_len, attn);
  gru_scan<<<256, 512, 0, stream>>>(wcatbf, FWr, FW, Ub, attn, cbf);
  next_mem_gemm<<<512, 256, 0, stream>>>(pmbf, cbf, qbf, nmbf, nmb, out);
}